// Round 10
// baseline (229.089 us; speedup 1.0000x reference)
//
#include <hip/hip_runtime.h>
#include <math.h>

typedef _Float16 f16;
typedef _Float16 f16x8 __attribute__((ext_vector_type(8)));
typedef float f32x4 __attribute__((ext_vector_type(4)));
typedef unsigned u32x2 __attribute__((ext_vector_type(2)));

#define B_  4
#define N_  2048
#define C_  128
#define NS_ 64

// ---- workspace layout (bytes) ----
#define WS_FEATNC 0u          // B*N*C f32 = 4194304
#define WS_IDX    4194304u    // B*N*NS u16 = 1048576
#define WS_W1P    5242880u    // 4 slices * 16384 = 65536
#define WS_W2P    5308416u    // 4 slices * 16384 = 65536

// ---- mlp LDS layout (bytes), total 67584 -> 2 x 512-thr blocks/CU ----
#define LDS_H    0            // h: 4 slots x 4096 = 16384 (a1 halves overlay; a2 f32 overlays H+W)
#define LDS_W    16384        // weight triple-buffer 3 x 16384 = 49152 (ends 65536)
#define LDS_GX   65536        // [64][3] f32 = 768
#define LDS_QF   66304        // [128] f32 = 512
#define LDS_IDX  66816        // 256 (RED overlays after gather)
#define LDS_RED  66816
#define LDS_W3   67072        // 512
#define LDS_TOTAL 67584

#define PHASE_BAR2() asm volatile("s_waitcnt vmcnt(2) lgkmcnt(0)\ns_barrier" ::: "memory")
#define PHASE_BAR0() asm volatile("s_waitcnt vmcnt(0) lgkmcnt(0)\ns_barrier" ::: "memory")
#define LBAR()       asm volatile("s_waitcnt lgkmcnt(0)\ns_barrier" ::: "memory")

__device__ __forceinline__ void gl_lds16(const char* gp, char* lp) {
  __builtin_amdgcn_global_load_lds(
      (const __attribute__((address_space(1))) unsigned int*)gp,
      (__attribute__((address_space(3))) unsigned int*)lp, 16, 0, 0);
}

// pack two floats as adjacent f16 (RTN)
__device__ __forceinline__ unsigned pk2(float a, float b) {
  union { f16 h[2]; unsigned u; } cv;
  cv.h[0] = (f16)a; cv.h[1] = (f16)b;
  return cv.u;
}

// ---------------------------------------------------------------------------
// prep: feat (B,C,N)->(B,N,C) f32; W1 feature-cols -> 4 K-slices (32 ch each)
// [256 o][16 ch-pair slots] f16 swizzled (row 64B); W2 -> 4 K-slices (64 ch)
// [128 p][32 pair slots] (row 128B). Images are exact LDS bytes for linear
// global_load_lds staging.
// ---------------------------------------------------------------------------
__global__ __launch_bounds__(256) void prep_kernel(
    const float* __restrict__ feat, const float* __restrict__ W1,
    const float* __restrict__ W2, float* __restrict__ feat_nc,
    char* __restrict__ W1p, char* __restrict__ W2p)
{
  int i = blockIdx.x * 256 + threadIdx.x;
  {
    int n = i & (N_ - 1);
    int bc = i >> 11;
    int c = bc & (C_ - 1);
    int b = bc >> 7;
    feat_nc[(size_t)((b << 11) + n) * C_ + c] = feat[i];
  }
  if (i < 16384) {   // W1: g = slice (32 ch), [o 0..255][j 0..15]; ch = 3+32g+2j
    int g = i >> 12, r = i & 4095, o = r >> 4, j = r & 15;
    const float* row = W1 + o * 131 + 3 + g * 32 + 2 * j;
    unsigned byte = ((unsigned)(o * 64 + j * 4)) ^ ((unsigned)(((o >> 1) & 7) << 4));
    *(unsigned*)(W1p + (size_t)g * 16384 + byte) = pk2(row[0], row[1]);
  }
  if (i < 16384) {   // W2: ko = slice (64 ch), [p 0..127][j 0..31]; o = 64ko+2j
    int ko = i >> 12, r = i & 4095, p = r >> 5, j = r & 31;
    int o = ko * 64 + 2 * j;
    unsigned byte = ((unsigned)(p * 128 + j * 4)) ^ ((unsigned)(((p >> 1) & 7) << 4));
    *(unsigned*)(W2p + (size_t)ko * 16384 + byte) = pk2(W2[p * 256 + o], W2[p * 256 + o + 1]);
  }
}

// ---------------------------------------------------------------------------
// ball query (fp64-exact membership), output u16
// ---------------------------------------------------------------------------
__global__ __launch_bounds__(256) void ballquery_kernel(
    const float* __restrict__ xyz, unsigned short* __restrict__ idxout)
{
  __shared__ float  xl[N_ * 3];
  __shared__ double sq[N_];
  __shared__ int    ibuf[4][NS_];

  const int b  = blockIdx.x >> 9;
  const int ng = blockIdx.x & 511;
  const int t  = threadIdx.x;
  const float* xb = xyz + (size_t)b * N_ * 3;

  for (int i = t; i < N_ * 3; i += 256) xl[i] = xb[i];
  __syncthreads();
  for (int i = t; i < N_; i += 256) {
    double x = (double)xl[3*i], y = (double)xl[3*i+1], z = (double)xl[3*i+2];
    sq[i] = x*x + y*y + z*z;
  }
  __syncthreads();

  const int wv = t >> 6, lane = t & 63;
  const int n = ng * 4 + wv;
  const double xn = (double)xl[3*n], yn = (double)xl[3*n+1], zn = (double)xl[3*n+2];
  const double sn = sq[n];

  int cnt = 0;
  for (int mb = 0; mb < N_; mb += 64) {
    int m = mb + lane;
    double dot = xn*(double)xl[3*m] + yn*(double)xl[3*m+1] + zn*(double)xl[3*m+2];
    double d2 = (sn + sq[m]) - 2.0 * dot;
    bool hit = d2 < 0.0625;
    unsigned long long mask = __ballot(hit);
    int pos = __popcll(mask & ((1ULL << lane) - 1ULL));
    int slot = cnt + pos;
    if (hit && slot < NS_) ibuf[wv][slot] = m;
    cnt += (int)__popcll(mask);
    if (cnt >= NS_) break;
  }
  asm volatile("s_waitcnt lgkmcnt(0)" ::: "memory");
  int total = cnt < NS_ ? cnt : NS_;
  int v = ibuf[wv][lane < total ? lane : 0];
  idxout[((size_t)b * N_ + n) * NS_ + lane] = (unsigned short)v;
}

// ---------------------------------------------------------------------------
// MLP: pure-f16 MFMA, 512-thread blocks (8 waves), target 2 blocks/CU.
// __launch_bounds__(512, 2): min-waves sets the unified VGPR budget (512/min);
// min=4 split the file 64 arch + 64 acc and spilled 425MB (R6/R8/R9).
// min=2 gives the allocator room; actual usage (~120 total) still permits
// 4 waves/EU at runtime. GEMM2 a-frags loaded per-cluster to cut peak arch
// pressure. 8 uniform phases, W triple-buffer, counted vmcnt(2) prefetch.
// ---------------------------------------------------------------------------
__global__ __launch_bounds__(512, 2)
void mlp_kernel(
    const float* __restrict__ xyz, const float* __restrict__ feat_nc,
    const char* __restrict__ w1p, const char* __restrict__ w2p,
    const unsigned short* __restrict__ idxg,
    const float* __restrict__ W1g, const float* __restrict__ W3g,
    const float* __restrict__ g1, const float* __restrict__ b1,
    const float* __restrict__ g2, const float* __restrict__ b2,
    const float* __restrict__ g3, const float* __restrict__ b3,
    float* __restrict__ out)
{
  __shared__ __attribute__((aligned(128))) char lds[LDS_TOTAL];

  const int bidRaw = blockIdx.x;
  const int bn = ((bidRaw & 7) << 10) + (bidRaw >> 3);   // XCD swizzle (bijective)
  const int b = bn >> 11;
  const int n = bn & (N_ - 1);
  const int t = threadIdx.x;
  const int w = t >> 6, lane = t & 63;
  const int l15 = lane & 15, lg = lane >> 4;
  const unsigned swzl = (unsigned)(((l15 >> 1) & 7) << 4);
  const unsigned labase = ((unsigned)(l15 * 64 + lg * 16)) ^ swzl;
  const unsigned w2b0 = ((unsigned)(l15 * 128 + lg * 16)) ^ swzl;        // k 0..31
  const unsigned w2b1 = ((unsigned)(l15 * 128 + 64 + lg * 16)) ^ swzl;   // k 32..63 (bit6 inside XOR)
  const float inv = 1.0f / sqrtf(1.0f + 1e-5f);

  float gg1v[2], bo1v[2], wx[2][3];
  #pragma unroll
  for (int nt2 = 0; nt2 < 2; ++nt2) {
    int o = 32 * w + nt2 * 16 + l15;
    gg1v[nt2] = g1[o] * inv; bo1v[nt2] = b1[o];
    #pragma unroll
    for (int c = 0; c < 3; ++c) wx[nt2][c] = W1g[o * 131 + c];
  }
  const int prow = 16 * w + l15;
  const float gg2 = g2[prow] * inv, bo2 = b2[prow];
  const float g3c = g3[0] * inv, b3c = b3[0];
  const float xn0 = xyz[(size_t)bn*3+0], xn1 = xyz[(size_t)bn*3+1], xn2 = xyz[(size_t)bn*3+2];

  auto STAGE = [&](int sl) {
    const char* gp = (sl < 4 ? w1p + (size_t)sl * 16384
                             : w2p + (size_t)(sl - 4) * 16384) + t * 16;
    char* lp = lds + LDS_W + (sl % 3) * 16384 + (w << 10);
    gl_lds16(gp, lp);
    gl_lds16(gp + 8192, lp + 8192);
  };

  // epilogue1: wave writes its 32 a1 channels into h slot (w&3), f16 swizzled
  f32x4 acc1[4][2];
  f32x4 acc2[4] = {};
  auto EPI1 = [&]() {
    const int slot = w & 3;
    #pragma unroll
    for (int mt = 0; mt < 4; ++mt)
      #pragma unroll
      for (int nt2 = 0; nt2 < 2; ++nt2)
        #pragma unroll
        for (int r = 0; r < 4; ++r) {
          int s = mt * 16 + lg * 4 + r;
          float a = fmaf(acc1[mt][nt2][r], gg1v[nt2], bo1v[nt2]);
          a = a > 0.0f ? a : 0.0f;
          unsigned byte = (unsigned)(slot * 4096)
            + (((unsigned)(s * 64 + (nt2 * 16 + l15) * 2)) ^ ((unsigned)(((s >> 1) & 7) << 4))
               ^ ((unsigned)(slot << 4)));
          *(f16*)(lds + LDS_H + byte) = (f16)a;
        }
  };

  // ---- prologue ----
  STAGE(0); STAGE(1);
  if (t < 64) ((int*)(lds + LDS_IDX))[t] = (int)idxg[(size_t)bn * 64 + t];
  if (t < 128) ((float*)(lds + LDS_QF))[t] = feat_nc[(size_t)bn * C_ + t];
  if (t < 128) ((float*)(lds + LDS_W3))[t] = W3g[t];
  LBAR();

  const int* idxl = (const int*)(lds + LDS_IDX);
  const float* qf = (const float*)(lds + LDS_QF);

  // gather features -> h f16 (4 channels per b64 write), 4 iters
  #pragma unroll
  for (int k = 0; k < 4; ++k) {
    int i = t + k * 512;
    int s = i >> 5, q4 = i & 31;
    int m = idxl[s];
    f32x4 f = *(const f32x4*)(feat_nc + ((size_t)b * N_ + m) * C_ + q4 * 4);
    int j4 = q4 * 4;
    float d0 = f[0] - qf[j4 + 0];
    float d1 = f[1] - qf[j4 + 1];
    float d2 = f[2] - qf[j4 + 2];
    float d3 = f[3] - qf[j4 + 3];
    int g = q4 >> 3;
    unsigned byte = (unsigned)(g * 4096)
      + (((unsigned)(s * 64 + (q4 & 7) * 8)) ^ ((unsigned)(((s >> 1) & 7) << 4))
         ^ ((unsigned)((g & 3) << 4)));
    u32x2 v;
    v.x = pk2(d0 * d0, d1 * d1);
    v.y = pk2(d2 * d2, d3 * d3);
    *(u32x2*)(lds + LDS_H + byte) = v;
  }
  // gather xyz -> GX (relative coords; also feeds VALU z1 contribution)
  if (t < 192) {
    int s = t & 63, c = t >> 6;
    int m = idxl[s];
    float p = xyz[((size_t)b * N_ + m) * 3 + c];
    float xnc = (c == 0) ? xn0 : (c == 1 ? xn1 : xn2);
    ((float*)(lds + LDS_GX))[s * 3 + c] = p - xnc;
  }
  LBAR();

  // ---- xyz-channel contribution: acc1 init on VALU ----
  {
    const float* gx = (const float*)(lds + LDS_GX);
    #pragma unroll
    for (int mt = 0; mt < 4; ++mt)
      #pragma unroll
      for (int r = 0; r < 4; ++r) {
        int s = mt * 16 + lg * 4 + r;
        float d0 = gx[s * 3 + 0] - xn0;
        float d1 = gx[s * 3 + 1] - xn1;
        float d2 = gx[s * 3 + 2] - xn2;
        d0 *= d0; d1 *= d1; d2 *= d2;
        #pragma unroll
        for (int nt2 = 0; nt2 < 2; ++nt2)
          acc1[mt][nt2][r] = fmaf(wx[nt2][0], d0, fmaf(wx[nt2][1], d1, wx[nt2][2] * d2));
      }
  }

  // ---- GEMM1: phases 0..3 (K=32 each) ----
  #pragma unroll
  for (int p = 0; p < 4; ++p) {
    STAGE(p + 2);                               // S2..S5
    const char* hb = lds + LDS_H + p * 4096;
    const unsigned gxr = ((unsigned)p) << 4;
    f16x8 af[4];
    #pragma unroll
    for (int mt = 0; mt < 4; ++mt)
      af[mt] = *(const f16x8*)(hb + mt * 1024 + (labase ^ gxr));
    const char* wb = lds + LDS_W + (p % 3) * 16384 + w * 2048;
    f16x8 bf0 = *(const f16x8*)(wb + labase);
    f16x8 bf1 = *(const f16x8*)(wb + 1024 + labase);
    __builtin_amdgcn_s_setprio(1);
    #pragma unroll
    for (int mt = 0; mt < 4; ++mt) {
      acc1[mt][0] = __builtin_amdgcn_mfma_f32_16x16x32_f16(af[mt], bf0, acc1[mt][0], 0, 0, 0);
      acc1[mt][1] = __builtin_amdgcn_mfma_f32_16x16x32_f16(af[mt], bf1, acc1[mt][1], 0, 0, 0);
    }
    __builtin_amdgcn_s_setprio(0);
    PHASE_BAR2();
  }

  // a1 half0 (o<128): waves 0..3
  if (w < 4) EPI1();
  LBAR();

  // ---- GEMM2: phases 4..7 (K=64 each); a-frags loaded per MFMA cluster ----
  #pragma unroll
  for (int ko = 0; ko < 4; ++ko) {
    if (ko < 2) STAGE(6 + ko);                  // S6, S7
    const char* wb = lds + LDS_W + ((4 + ko) % 3) * 16384 + w * 2048;
    f16x8 bf0 = *(const f16x8*)(wb + w2b0);
    f16x8 bf1 = *(const f16x8*)(wb + w2b1);
    const int sl0 = (2 * ko) & 3, sl1 = (2 * ko + 1) & 3;
    {
      f16x8 a0f[4];
      #pragma unroll
      for (int mt = 0; mt < 4; ++mt)
        a0f[mt] = *(const f16x8*)(lds + LDS_H + sl0 * 4096 + mt * 1024 + (labase ^ (unsigned)(sl0 << 4)));
      __builtin_amdgcn_s_setprio(1);
      #pragma unroll
      for (int mt = 0; mt < 4; ++mt)
        acc2[mt] = __builtin_amdgcn_mfma_f32_16x16x32_f16(a0f[mt], bf0, acc2[mt], 0, 0, 0);
      __builtin_amdgcn_s_setprio(0);
    }
    {
      f16x8 a1f[4];
      #pragma unroll
      for (int mt = 0; mt < 4; ++mt)
        a1f[mt] = *(const f16x8*)(lds + LDS_H + sl1 * 4096 + mt * 1024 + (labase ^ (unsigned)(sl1 << 4)));
      __builtin_amdgcn_s_setprio(1);
      #pragma unroll
      for (int mt = 0; mt < 4; ++mt)
        acc2[mt] = __builtin_amdgcn_mfma_f32_16x16x32_f16(a1f[mt], bf1, acc2[mt], 0, 0, 0);
      __builtin_amdgcn_s_setprio(0);
    }
    if (ko == 0) {
      PHASE_BAR2();
    } else if (ko == 1) {
      PHASE_BAR2();
      if (w >= 4) EPI1();                       // a1 half1 (o>=128) into slots 0..3
      LBAR();
    } else if (ko == 2) {
      PHASE_BAR0();
    } else {
      LBAR();                                   // before a2 overlay writes
    }
  }

  // ---- epilogue2: a2 = relu(bn2(z2)) f32, rows stride 528B (overlays H+W) ----
  #pragma unroll
  for (int mt = 0; mt < 4; ++mt)
    #pragma unroll
    for (int r = 0; r < 4; ++r) {
      int s = mt * 16 + lg * 4 + r;
      float a = fmaf(acc2[mt][r], gg2, bo2);
      a = a > 0.0f ? a : 0.0f;
      *(float*)(lds + s * 528 + prow * 4) = a;
    }
  LBAR();

  // ---- GEMM3 + weighted mean ----
  {
    int s3 = t >> 3, q3 = t & 7;                // 8 threads per sample
    const float* a2row = (const float*)lds + s3 * 132;
    const float* w3r = (const float*)(lds + LDS_W3);
    float z3 = 0.0f;
    #pragma unroll
    for (int i = 0; i < 4; ++i) {
      f32x4 av = *(const f32x4*)(a2row + q3 * 16 + i * 4);
      f32x4 wv = *(const f32x4*)(w3r + q3 * 16 + i * 4);
      z3 = fmaf(av[0], wv[0], z3); z3 = fmaf(av[1], wv[1], z3);
      z3 = fmaf(av[2], wv[2], z3); z3 = fmaf(av[3], wv[3], z3);
    }
    z3 += __shfl_xor(z3, 1);
    z3 += __shfl_xor(z3, 2);
    z3 += __shfl_xor(z3, 4);
    float wgt = fmaf(g3c, z3, b3c);
    wgt = wgt > 0.0f ? wgt : 0.0f;
    float v0 = 0.f, v1 = 0.f, v2 = 0.f, v3 = 0.f;
    if (q3 == 0) {
      const float* gx = (const float*)(lds + LDS_GX) + s3 * 3;
      v0 = gx[0] * wgt; v1 = gx[1] * wgt; v2 = gx[2] * wgt; v3 = wgt;
    }
    #pragma unroll
    for (int off = 8; off < 64; off <<= 1) {
      v0 += __shfl_xor(v0, off); v1 += __shfl_xor(v1, off);
      v2 += __shfl_xor(v2, off); v3 += __shfl_xor(v3, off);
    }
    if (lane == 0) {
      float* red = (float*)(lds + LDS_RED);
      red[w * 4 + 0] = v0; red[w * 4 + 1] = v1;
      red[w * 4 + 2] = v2; red[w * 4 + 3] = v3;
    }
    LBAR();
    if (t == 0) {
      const float* red = (const float*)(lds + LDS_RED);
      float n0 = 0.f, n1 = 0.f, n2 = 0.f, dd = 0.f;
      #pragma unroll
      for (int i = 0; i < 8; ++i) {
        n0 += red[i * 4 + 0]; n1 += red[i * 4 + 1];
        n2 += red[i * 4 + 2]; dd += red[i * 4 + 3];
      }
      out[(size_t)(b * 3 + 0) * N_ + n] = n0 / dd;
      out[(size_t)(b * 3 + 1) * N_ + n] = n1 / dd;
      out[(size_t)(b * 3 + 2) * N_ + n] = n2 / dd;
    }
  }
}

extern "C" void kernel_launch(void* const* d_in, const int* in_sizes, int n_in,
                              void* d_out, int out_size, void* d_ws, size_t ws_size,
                              hipStream_t stream) {
  (void)in_sizes; (void)n_in; (void)out_size; (void)ws_size;
  const float* xyz      = (const float*)d_in[0];
  const float* features = (const float*)d_in[1];
  const float* W1 = (const float*)d_in[2];
  const float* W2 = (const float*)d_in[3];
  const float* W3 = (const float*)d_in[4];
  const float* g1 = (const float*)d_in[5];
  const float* g2 = (const float*)d_in[6];
  const float* g3 = (const float*)d_in[7];
  const float* b1 = (const float*)d_in[8];
  const float* b2 = (const float*)d_in[9];
  const float* b3 = (const float*)d_in[10];
  float* out = (float*)d_out;

  char* ws = (char*)d_ws;
  float* feat_nc      = (float*)(ws + WS_FEATNC);
  unsigned short* idx = (unsigned short*)(ws + WS_IDX);
  char* W1p           = ws + WS_W1P;
  char* W2p           = ws + WS_W2P;

  prep_kernel<<<dim3((B_ * C_ * N_) / 256), dim3(256), 0, stream>>>(
      features, W1, W2, feat_nc, W1p, W2p);
  ballquery_kernel<<<dim3(B_ * N_ / 4), dim3(256), 0, stream>>>(xyz, idx);
  mlp_kernel<<<dim3(B_ * N_), dim3(512), 0, stream>>>(
      xyz, feat_nc, W1p, W2p, idx, W1, W3, g1, b1, g2, b2, g3, b3, out);
}

// Round 11
// 147.425 us; speedup vs baseline: 1.5539x; 1.5539x over previous
//
#include <hip/hip_runtime.h>
#include <math.h>

typedef _Float16 f16;
typedef _Float16 f16x8 __attribute__((ext_vector_type(8)));
typedef float f32x4 __attribute__((ext_vector_type(4)));
typedef unsigned u32x2 __attribute__((ext_vector_type(2)));

#define B_  4
#define N_  2048
#define C_  128
#define NS_ 64

// ---- workspace layout (bytes) ----
#define WS_FEATNC 0u          // B*N*C f32 = 4194304
#define WS_IDX    4194304u    // B*N*NS u16 = 1048576
#define WS_W1P    5242880u    // 8 slices * 8192 = 65536
#define WS_W2P    5308416u    // 8 slices * 8192 = 65536

// ---- mlp LDS layout (bytes), total 35840 -> 4 blocks/CU ----
#define OFF_H   0             // h: 4 groups x 4096 = 16384 (a1 halves overlay)
#define OFF_W   16384         // weight dbuf 2 x 8192
#define OFF_A2  0             // 64*132*4 = 33792 f32 (overlays H+W at the end)
#define OFF_GX  33792         // [64][3] f32 = 768
#define OFF_QF  34560         // [128] f32 = 512
#define OFF_IDX 35072         // 256 (RED overlays after gather)
#define OFF_RED 35072
#define OFF_W3  35328         // 512
#define LDS_TOTAL 35840

__device__ __forceinline__ void gl_lds16(const char* gp, char* lp) {
  __builtin_amdgcn_global_load_lds(
      (const __attribute__((address_space(1))) unsigned int*)gp,
      (__attribute__((address_space(3))) unsigned int*)lp, 16, 0, 0);
}

// pack two floats as adjacent f16 (RTN)
__device__ __forceinline__ unsigned pk2(float a, float b) {
  union { f16 h[2]; unsigned u; } cv;
  cv.h[0] = (f16)a; cv.h[1] = (f16)b;
  return cv.u;
}

// ---------------------------------------------------------------------------
// prep: feat (B,C,N)->(B,N,C) f32; W1 feature-cols -> 8 slices (g 0..3, oh
// 0..1): [128 o'][16 ch-pair slots] f16 swizzled; W2 -> 8 o-slices [128 p]
// [16 slots]. Images are exact LDS bytes for linear global_load_lds staging.
// ---------------------------------------------------------------------------
__global__ __launch_bounds__(256) void prep_kernel(
    const float* __restrict__ feat, const float* __restrict__ W1,
    const float* __restrict__ W2, float* __restrict__ feat_nc,
    char* __restrict__ W1p, char* __restrict__ W2p)
{
  int i = blockIdx.x * 256 + threadIdx.x;
  {
    int n = i & (N_ - 1);
    int bc = i >> 11;
    int c = bc & (C_ - 1);
    int b = bc >> 7;
    feat_nc[(size_t)((b << 11) + n) * C_ + c] = feat[i];
  }
  if (i < 8 * 2048) {   // W1: sl = g*2+oh; [o' 0..127][j 0..15]; ch = g*32+2j
    int sl = i >> 11; int r = i & 2047; int op = r >> 4; int j = r & 15;
    int g = sl >> 1, oh = sl & 1;
    int o = oh * 128 + op;
    const float* row = W1 + o * 131 + 3 + g * 32 + 2 * j;
    unsigned byte = ((unsigned)(op * 64 + j * 4)) ^ ((unsigned)(((op >> 1) & 7) << 4));
    *(unsigned*)(W1p + (size_t)sl * 8192 + byte) = pk2(row[0], row[1]);
  }
  if (i < 8 * 2048) {   // W2: ko slices; [p 0..127][j 0..15]; o = ko*32+2j
    int ko = i >> 11; int r = i & 2047; int p = r >> 4; int j = r & 15;
    int o = ko * 32 + 2 * j;
    unsigned byte = ((unsigned)(p * 64 + j * 4)) ^ ((unsigned)(((p >> 1) & 7) << 4));
    *(unsigned*)(W2p + (size_t)ko * 8192 + byte) = pk2(W2[p * 256 + o], W2[p * 256 + o + 1]);
  }
}

// ---------------------------------------------------------------------------
// ball query (fp64-exact membership), output u16
// ---------------------------------------------------------------------------
__global__ __launch_bounds__(256) void ballquery_kernel(
    const float* __restrict__ xyz, unsigned short* __restrict__ idxout)
{
  __shared__ float  xl[N_ * 3];
  __shared__ double sq[N_];
  __shared__ int    ibuf[4][NS_];

  const int b  = blockIdx.x >> 9;
  const int ng = blockIdx.x & 511;
  const int t  = threadIdx.x;
  const float* xb = xyz + (size_t)b * N_ * 3;

  for (int i = t; i < N_ * 3; i += 256) xl[i] = xb[i];
  __syncthreads();
  for (int i = t; i < N_; i += 256) {
    double x = (double)xl[3*i], y = (double)xl[3*i+1], z = (double)xl[3*i+2];
    sq[i] = x*x + y*y + z*z;
  }
  __syncthreads();

  const int wv = t >> 6, lane = t & 63;
  const int n = ng * 4 + wv;
  const double xn = (double)xl[3*n], yn = (double)xl[3*n+1], zn = (double)xl[3*n+2];
  const double sn = sq[n];

  int cnt = 0;
  for (int mb = 0; mb < N_; mb += 64) {
    int m = mb + lane;
    double dot = xn*(double)xl[3*m] + yn*(double)xl[3*m+1] + zn*(double)xl[3*m+2];
    double d2 = (sn + sq[m]) - 2.0 * dot;
    bool hit = d2 < 0.0625;
    unsigned long long mask = __ballot(hit);
    int pos = __popcll(mask & ((1ULL << lane) - 1ULL));
    int slot = cnt + pos;
    if (hit && slot < NS_) ibuf[wv][slot] = m;
    cnt += (int)__popcll(mask);
    if (cnt >= NS_) break;
  }
  asm volatile("s_waitcnt lgkmcnt(0)" ::: "memory");
  int total = cnt < NS_ ? cnt : NS_;
  int v = ibuf[wv][lane < total ? lane : 0];
  idxout[((size_t)b * N_ + n) * NS_ + lane] = (unsigned short)v;
}

// ---------------------------------------------------------------------------
// MLP: pure-f16 MFMA (R6 structure). 256 threads, 35840B LDS -> 4 blocks/CU.
// __launch_bounds__(256,3): min=3 -> VGPR budget 170 -> no spill (R5-proven);
// min=4 (R6) forced a 64-arch allocation and spilled 194MB. Occupancy comes
// from LDS (4 blocks) x VGPR (~84 -> 4 waves/SIMD) = 16 waves/CU.
// GEMM1 K=128 (8 phases: 4 ch-groups x 2 o-halves); GEMM2 K=256 (8 phases,
// a1 half-split). xyz channels on VALU (fp32-exact acc1 init).
// ---------------------------------------------------------------------------
__global__ __launch_bounds__(256, 3) void mlp_kernel(
    const float* __restrict__ xyz, const float* __restrict__ feat_nc,
    const char* __restrict__ w1p, const char* __restrict__ w2p,
    const unsigned short* __restrict__ idxg,
    const float* __restrict__ W1g, const float* __restrict__ W3g,
    const float* __restrict__ g1, const float* __restrict__ b1,
    const float* __restrict__ g2, const float* __restrict__ b2,
    const float* __restrict__ g3, const float* __restrict__ b3,
    float* __restrict__ out)
{
  __shared__ __attribute__((aligned(128))) char lds[LDS_TOTAL];

  const int bidRaw = blockIdx.x;
  const int bn = ((bidRaw & 7) << 10) + (bidRaw >> 3);   // XCD swizzle (bijective)
  const int b = bn >> 11;
  const int n = bn & (N_ - 1);
  const int t = threadIdx.x;
  const int w = t >> 6, lane = t & 63;
  const int l15 = lane & 15, lg = lane >> 4;
  const unsigned labase = ((unsigned)(l15 * 64 + lg * 16)) ^ ((unsigned)(((l15 >> 1) & 7) << 4));
  const float inv = 1.0f / sqrtf(1.0f + 1e-5f);

  float gg1v[4], bo1v[4];
  float wx[4][3];
  #pragma unroll
  for (int nt = 0; nt < 4; ++nt) {
    int o = (nt >> 1) * 128 + 32 * w + (nt & 1) * 16 + l15;
    gg1v[nt] = g1[o] * inv; bo1v[nt] = b1[o];
    #pragma unroll
    for (int c = 0; c < 3; ++c) wx[nt][c] = W1g[o * 131 + c];
  }
  float gg2v[2], bo2v[2];
  #pragma unroll
  for (int nt = 0; nt < 2; ++nt) {
    int p = 32 * w + nt * 16 + l15;
    gg2v[nt] = g2[p] * inv; bo2v[nt] = b2[p];
  }
  const float g3c = g3[0] * inv, b3c = b3[0];
  const float xn0 = xyz[(size_t)bn*3+0], xn1 = xyz[(size_t)bn*3+1], xn2 = xyz[(size_t)bn*3+2];

  auto STAGE = [&](int sl) {
    const char* gp = (sl < 8 ? w1p + (size_t)sl * 8192
                             : w2p + (size_t)(sl - 8) * 8192) + t * 16;
    char* lp = lds + OFF_W + ((sl & 1) << 13) + (w << 10);
    gl_lds16(gp, lp);
    gl_lds16(gp + 4096, lp + 4096);
  };

  f32x4 acc1[4][4];
  f32x4 acc2[4][2] = {};

  // ---- prologue ----
  STAGE(0);
  if (t < 64) ((int*)(lds + OFF_IDX))[t] = (int)idxg[(size_t)bn * 64 + t];
  if (t < 128) ((float*)(lds + OFF_QF))[t] = feat_nc[(size_t)bn * C_ + t];
  if (t < 128) ((float*)(lds + OFF_W3))[t] = W3g[t];
  __syncthreads();

  const int* idxl = (const int*)(lds + OFF_IDX);
  const float* qf = (const float*)(lds + OFF_QF);

  // gather features -> h f16 (4 channels per b64 write)
  #pragma unroll
  for (int k = 0; k < 8; ++k) {
    int i = t + k * 256;
    int s = i >> 5, q4 = i & 31;
    int m = idxl[s];
    f32x4 f = *(const f32x4*)(feat_nc + ((size_t)b * N_ + m) * C_ + q4 * 4);
    int j4 = q4 * 4;
    float d0 = f[0] - qf[j4 + 0];
    float d1 = f[1] - qf[j4 + 1];
    float d2 = f[2] - qf[j4 + 2];
    float d3 = f[3] - qf[j4 + 3];
    int g = q4 >> 3;
    unsigned byte = (unsigned)(g * 4096)
      + (((unsigned)(s * 64 + (q4 & 7) * 8)) ^ ((unsigned)(((s >> 1) & 7) << 4))
         ^ ((unsigned)((g & 3) << 4)));
    u32x2 v;
    v.x = pk2(d0 * d0, d1 * d1);
    v.y = pk2(d2 * d2, d3 * d3);
    *(u32x2*)(lds + OFF_H + byte) = v;
  }
  // gather xyz -> GX (relative coords; also feeds VALU z1 contribution)
  if (t < 192) {
    int s = t & 63, c = t >> 6;
    int m = idxl[s];
    float p = xyz[((size_t)b * N_ + m) * 3 + c];
    float xnc = (c == 0) ? xn0 : (c == 1 ? xn1 : xn2);
    ((float*)(lds + OFF_GX))[s * 3 + c] = p - xnc;
  }
  asm volatile("s_waitcnt vmcnt(0)" ::: "memory");
  __syncthreads();

  // ---- xyz-channel contribution: acc1 init on VALU (h_xyz = (p - 2*xn)^2) ----
  {
    const float* gx = (const float*)(lds + OFF_GX);
    #pragma unroll
    for (int mt = 0; mt < 4; ++mt)
      #pragma unroll
      for (int r = 0; r < 4; ++r) {
        int s = mt * 16 + lg * 4 + r;
        float d0 = gx[s * 3 + 0] - xn0;
        float d1 = gx[s * 3 + 1] - xn1;
        float d2 = gx[s * 3 + 2] - xn2;
        d0 *= d0; d1 *= d1; d2 *= d2;
        #pragma unroll
        for (int nt = 0; nt < 4; ++nt)
          acc1[mt][nt][r] = fmaf(wx[nt][0], d0, fmaf(wx[nt][1], d1, wx[nt][2] * d2));
      }
  }

  // ---- GEMM1: 8 phases (g 0..3 x oh 0..1) ----
  f16x8 af[4];
  #pragma unroll
  for (int p = 0; p < 8; ++p) {
    const int g = p >> 1, oh = p & 1;
    STAGE(p + 1);
    if (oh == 0) {
      const char* hb = lds + OFF_H + g * 4096;
      const unsigned gx4 = ((unsigned)(g & 3)) << 4;
      #pragma unroll
      for (int mt = 0; mt < 4; ++mt)
        af[mt] = *(const f16x8*)(hb + mt * 1024 + (labase ^ gx4));
    }
    const char* wb = lds + OFF_W + ((p & 1) << 13);
    f16x8 bf0 = *(const f16x8*)(wb + (32 * w) * 64 + labase);
    f16x8 bf1 = *(const f16x8*)(wb + (32 * w + 16) * 64 + labase);
    __builtin_amdgcn_s_setprio(1);
    #pragma unroll
    for (int mt = 0; mt < 4; ++mt) {
      acc1[mt][oh * 2 + 0] =
          __builtin_amdgcn_mfma_f32_16x16x32_f16(af[mt], bf0, acc1[mt][oh * 2 + 0], 0, 0, 0);
      acc1[mt][oh * 2 + 1] =
          __builtin_amdgcn_mfma_f32_16x16x32_f16(af[mt], bf1, acc1[mt][oh * 2 + 1], 0, 0, 0);
    }
    __builtin_amdgcn_s_setprio(0);
    asm volatile("s_waitcnt vmcnt(0)" ::: "memory");
    __syncthreads();
  }

  // ---- epilogue1: a1 (f16 singles) -> h region; wave w owns o-group w ----
  auto EPI1 = [&](int hf) {
    #pragma unroll
    for (int mt = 0; mt < 4; ++mt)
      #pragma unroll
      for (int nt2 = 0; nt2 < 2; ++nt2) {
        const int nt = hf * 2 + nt2;
        #pragma unroll
        for (int r = 0; r < 4; ++r) {
          int s = mt * 16 + lg * 4 + r;
          float a = fmaf(acc1[mt][nt][r], gg1v[nt], bo1v[nt]);
          a = a > 0.0f ? a : 0.0f;
          unsigned byte = (unsigned)(w * 4096)
            + (((unsigned)(s * 64 + nt2 * 32 + l15 * 2)) ^ ((unsigned)(((s >> 1) & 7) << 4))
               ^ ((unsigned)((w & 3) << 4)));
          *(f16*)(lds + OFF_H + byte) = (f16)a;
        }
      }
  };
  EPI1(0);
  __syncthreads();

  // ---- GEMM2: 8 phases, a1 half-split at ko==4 ----
  #pragma unroll
  for (int ko = 0; ko < 8; ++ko) {
    if (ko < 7) STAGE(9 + ko);
    const char* ab = lds + OFF_H + (ko & 3) * 4096;
    const unsigned gx4 = ((unsigned)(ko & 3)) << 4;
    f16x8 a2f[4];
    #pragma unroll
    for (int mt = 0; mt < 4; ++mt)
      a2f[mt] = *(const f16x8*)(ab + mt * 1024 + (labase ^ gx4));
    const char* wb = lds + OFF_W + ((ko & 1) << 13);
    f16x8 bf0 = *(const f16x8*)(wb + (32 * w) * 64 + labase);
    f16x8 bf1 = *(const f16x8*)(wb + (32 * w + 16) * 64 + labase);
    __builtin_amdgcn_s_setprio(1);
    #pragma unroll
    for (int mt = 0; mt < 4; ++mt) {
      acc2[mt][0] =
          __builtin_amdgcn_mfma_f32_16x16x32_f16(a2f[mt], bf0, acc2[mt][0], 0, 0, 0);
      acc2[mt][1] =
          __builtin_amdgcn_mfma_f32_16x16x32_f16(a2f[mt], bf1, acc2[mt][1], 0, 0, 0);
    }
    __builtin_amdgcn_s_setprio(0);
    asm volatile("s_waitcnt vmcnt(0)" ::: "memory");
    __syncthreads();
    if (ko == 3) {       // a1 half0 consumed -> write half1
      EPI1(1);
      __syncthreads();
    }
  }

  // ---- epilogue2: a2 = relu(bn2(z2)) f32, rows stride 528B (overlays H+W) ----
  #pragma unroll
  for (int mt = 0; mt < 4; ++mt)
    #pragma unroll
    for (int nt2 = 0; nt2 < 2; ++nt2) {
      int p2 = 32 * w + nt2 * 16 + l15;
      #pragma unroll
      for (int r = 0; r < 4; ++r) {
        int s = mt * 16 + lg * 4 + r;
        float a = fmaf(acc2[mt][nt2][r], gg2v[nt2], bo2v[nt2]);
        a = a > 0.0f ? a : 0.0f;
        *(float*)(lds + OFF_A2 + s * 528 + p2 * 4) = a;
      }
    }
  __syncthreads();

  // ---- GEMM3 + weighted mean ----
  {
    int s3 = t >> 2, q3 = t & 3;
    const float* a2row = (const float*)(lds + OFF_A2) + s3 * 132;
    const float* w3r = (const float*)(lds + OFF_W3);
    float z3 = 0.0f;
    #pragma unroll
    for (int i = 0; i < 8; ++i) {
      f32x4 av = *(const f32x4*)(a2row + q3 * 32 + i * 4);
      f32x4 wv = *(const f32x4*)(w3r + q3 * 32 + i * 4);
      z3 = fmaf(av[0], wv[0], z3); z3 = fmaf(av[1], wv[1], z3);
      z3 = fmaf(av[2], wv[2], z3); z3 = fmaf(av[3], wv[3], z3);
    }
    z3 += __shfl_xor(z3, 1);
    z3 += __shfl_xor(z3, 2);
    float wgt = fmaf(g3c, z3, b3c);
    wgt = wgt > 0.0f ? wgt : 0.0f;
    float v0 = 0.f, v1 = 0.f, v2 = 0.f, v3 = 0.f;
    if (q3 == 0) {
      const float* gx = (const float*)(lds + OFF_GX) + s3 * 3;
      v0 = gx[0] * wgt; v1 = gx[1] * wgt; v2 = gx[2] * wgt; v3 = wgt;
    }
    #pragma unroll
    for (int off = 4; off < 64; off <<= 1) {
      v0 += __shfl_xor(v0, off); v1 += __shfl_xor(v1, off);
      v2 += __shfl_xor(v2, off); v3 += __shfl_xor(v3, off);
    }
    if (lane == 0) {
      float* red = (float*)(lds + OFF_RED);
      red[w * 4 + 0] = v0; red[w * 4 + 1] = v1;
      red[w * 4 + 2] = v2; red[w * 4 + 3] = v3;
    }
    __syncthreads();
    if (t == 0) {
      const float* red = (const float*)(lds + OFF_RED);
      float n0 = red[0] + red[4] + red[8]  + red[12];
      float n1 = red[1] + red[5] + red[9]  + red[13];
      float n2 = red[2] + red[6] + red[10] + red[14];
      float dd = red[3] + red[7] + red[11] + red[15];
      out[(size_t)(b * 3 + 0) * N_ + n] = n0 / dd;
      out[(size_t)(b * 3 + 1) * N_ + n] = n1 / dd;
      out[(size_t)(b * 3 + 2) * N_ + n] = n2 / dd;
    }
  }
}

extern "C" void kernel_launch(void* const* d_in, const int* in_sizes, int n_in,
                              void* d_out, int out_size, void* d_ws, size_t ws_size,
                              hipStream_t stream) {
  (void)in_sizes; (void)n_in; (void)out_size; (void)ws_size;
  const float* xyz      = (const float*)d_in[0];
  const float* features = (const float*)d_in[1];
  const float* W1 = (const float*)d_in[2];
  const float* W2 = (const float*)d_in[3];
  const float* W3 = (const float*)d_in[4];
  const float* g1 = (const float*)d_in[5];
  const float* g2 = (const float*)d_in[6];
  const float* g3 = (const float*)d_in[7];
  const float* b1 = (const float*)d_in[8];
  const float* b2 = (const float*)d_in[9];
  const float* b3 = (const float*)d_in[10];
  float* out = (float*)d_out;

  char* ws = (char*)d_ws;
  float* feat_nc      = (float*)(ws + WS_FEATNC);
  unsigned short* idx = (unsigned short*)(ws + WS_IDX);
  char* W1p           = ws + WS_W1P;
  char* W2p           = ws + WS_W2P;

  prep_kernel<<<dim3((B_ * C_ * N_) / 256), dim3(256), 0, stream>>>(
      features, W1, W2, feat_nc, W1p, W2p);
  ballquery_kernel<<<dim3(B_ * N_ / 4), dim3(256), 0, stream>>>(xyz, idx);
  mlp_kernel<<<dim3(B_ * N_), dim3(256), 0, stream>>>(
      xyz, feat_nc, W1p, W2p, idx, W1, W3, g1, b1, g2, b2, g3, b3, out);
}

// Round 12
// 141.440 us; speedup vs baseline: 1.6197x; 1.0423x over previous
//
#include <hip/hip_runtime.h>
#include <math.h>

typedef _Float16 f16;
typedef _Float16 f16x8 __attribute__((ext_vector_type(8)));
typedef float f32x4 __attribute__((ext_vector_type(4)));

#define B_  4
#define N_  2048
#define C_  128
#define NS_ 64

// ---- workspace layout (bytes) ----
#define WS_FEAT16 0u          // B*N*C f16 = 2097152
#define WS_IDX    2097152u    // B*N*NS u16 = 1048576
#define WS_W1P    3145728u    // 8 slices * 8192 = 65536
#define WS_W2P    3211264u    // 8 slices * 8192 = 65536

// ---- mlp LDS layout (bytes), total 35840 ----
#define OFF_H   0             // h: 4 groups x 4096 = 16384 (a1 halves overlay)
#define OFF_W   16384         // weight dbuf 2 x 8192
#define OFF_A2  0             // 64*132*4 = 33792 f32 (overlays H+W at the end)
#define OFF_GX  33792         // [64][3] f32 = 768
#define OFF_QF  34560         // [128] f16 = 256 (512 reserved)
#define OFF_IDX 35072         // 256 (RED overlays after gather)
#define OFF_RED 35072
#define OFF_W3  35328         // 512
#define LDS_TOTAL 35840

__device__ __forceinline__ void gl_lds16(const char* gp, char* lp) {
  __builtin_amdgcn_global_load_lds(
      (const __attribute__((address_space(1))) unsigned int*)gp,
      (__attribute__((address_space(3))) unsigned int*)lp, 16, 0, 0);
}

// pack two floats as adjacent f16 (RTN)
__device__ __forceinline__ unsigned pk2(float a, float b) {
  union { f16 h[2]; unsigned u; } cv;
  cv.h[0] = (f16)a; cv.h[1] = (f16)b;
  return cv.u;
}

// ---------------------------------------------------------------------------
// prep: feat (B,C,N) f32 -> feat16 (B,N,C) f16; W1 feature-cols -> 8 slices
// (g 0..3, oh 0..1): [128 o'][16 ch-pair slots] f16 swizzled; W2 -> 8
// o-slices [128 p][16 slots]. Weight images are exact LDS bytes for linear
// global_load_lds staging.
// ---------------------------------------------------------------------------
__global__ __launch_bounds__(256) void prep_kernel(
    const float* __restrict__ feat, const float* __restrict__ W1,
    const float* __restrict__ W2, f16* __restrict__ feat16,
    char* __restrict__ W1p, char* __restrict__ W2p)
{
  int i = blockIdx.x * 256 + threadIdx.x;
  {
    int n = i & (N_ - 1);
    int bc = i >> 11;
    int c = bc & (C_ - 1);
    int b = bc >> 7;
    feat16[(size_t)((b << 11) + n) * C_ + c] = (f16)feat[i];
  }
  if (i < 8 * 2048) {   // W1: sl = g*2+oh; [o' 0..127][j 0..15]; ch = g*32+2j
    int sl = i >> 11; int r = i & 2047; int op = r >> 4; int j = r & 15;
    int g = sl >> 1, oh = sl & 1;
    int o = oh * 128 + op;
    const float* row = W1 + o * 131 + 3 + g * 32 + 2 * j;
    unsigned byte = ((unsigned)(op * 64 + j * 4)) ^ ((unsigned)(((op >> 1) & 7) << 4));
    *(unsigned*)(W1p + (size_t)sl * 8192 + byte) = pk2(row[0], row[1]);
  }
  if (i < 8 * 2048) {   // W2: ko slices; [p 0..127][j 0..15]; o = ko*32+2j
    int ko = i >> 11; int r = i & 2047; int p = r >> 4; int j = r & 15;
    int o = ko * 32 + 2 * j;
    unsigned byte = ((unsigned)(p * 64 + j * 4)) ^ ((unsigned)(((p >> 1) & 7) << 4));
    *(unsigned*)(W2p + (size_t)ko * 8192 + byte) = pk2(W2[p * 256 + o], W2[p * 256 + o + 1]);
  }
}

// ---------------------------------------------------------------------------
// ball query (fp64-exact membership), output u16
// ---------------------------------------------------------------------------
__global__ __launch_bounds__(256) void ballquery_kernel(
    const float* __restrict__ xyz, unsigned short* __restrict__ idxout)
{
  __shared__ float  xl[N_ * 3];
  __shared__ double sq[N_];
  __shared__ int    ibuf[4][NS_];

  const int b  = blockIdx.x >> 9;
  const int ng = blockIdx.x & 511;
  const int t  = threadIdx.x;
  const float* xb = xyz + (size_t)b * N_ * 3;

  for (int i = t; i < N_ * 3; i += 256) xl[i] = xb[i];
  __syncthreads();
  for (int i = t; i < N_; i += 256) {
    double x = (double)xl[3*i], y = (double)xl[3*i+1], z = (double)xl[3*i+2];
    sq[i] = x*x + y*y + z*z;
  }
  __syncthreads();

  const int wv = t >> 6, lane = t & 63;
  const int n = ng * 4 + wv;
  const double xn = (double)xl[3*n], yn = (double)xl[3*n+1], zn = (double)xl[3*n+2];
  const double sn = sq[n];

  int cnt = 0;
  for (int mb = 0; mb < N_; mb += 64) {
    int m = mb + lane;
    double dot = xn*(double)xl[3*m] + yn*(double)xl[3*m+1] + zn*(double)xl[3*m+2];
    double d2 = (sn + sq[m]) - 2.0 * dot;
    bool hit = d2 < 0.0625;
    unsigned long long mask = __ballot(hit);
    int pos = __popcll(mask & ((1ULL << lane) - 1ULL));
    int slot = cnt + pos;
    if (hit && slot < NS_) ibuf[wv][slot] = m;
    cnt += (int)__popcll(mask);
    if (cnt >= NS_) break;
  }
  asm volatile("s_waitcnt lgkmcnt(0)" ::: "memory");
  int total = cnt < NS_ ? cnt : NS_;
  int v = ibuf[wv][lane < total ? lane : 0];
  idxout[((size_t)b * N_ + n) * NS_ + lane] = (unsigned short)v;
}

// ---------------------------------------------------------------------------
// MLP: pure-f16 MFMA (R11 structure) + packed-f16 gather. 256 threads,
// 35840B LDS, __launch_bounds__(256,3) (no spill, R5/R11-proven).
// Gather: feat16 f16x8 loads + v_pk_sub/v_pk_mul -> b128 h writes (no cvt).
// GEMM1 K=128 (8 phases: 4 ch-groups x 2 o-halves); GEMM2 K=256 (8 phases,
// a1 half-split). xyz channels on VALU (fp32-exact acc1 init).
// ---------------------------------------------------------------------------
__global__ __launch_bounds__(256, 3) void mlp_kernel(
    const float* __restrict__ xyz, const f16* __restrict__ feat16,
    const char* __restrict__ w1p, const char* __restrict__ w2p,
    const unsigned short* __restrict__ idxg,
    const float* __restrict__ W1g, const float* __restrict__ W3g,
    const float* __restrict__ g1, const float* __restrict__ b1,
    const float* __restrict__ g2, const float* __restrict__ b2,
    const float* __restrict__ g3, const float* __restrict__ b3,
    float* __restrict__ out)
{
  __shared__ __attribute__((aligned(128))) char lds[LDS_TOTAL];

  const int bidRaw = blockIdx.x;
  const int bn = ((bidRaw & 7) << 10) + (bidRaw >> 3);   // XCD swizzle (bijective)
  const int b = bn >> 11;
  const int n = bn & (N_ - 1);
  const int t = threadIdx.x;
  const int w = t >> 6, lane = t & 63;
  const int l15 = lane & 15, lg = lane >> 4;
  const unsigned labase = ((unsigned)(l15 * 64 + lg * 16)) ^ ((unsigned)(((l15 >> 1) & 7) << 4));
  const float inv = 1.0f / sqrtf(1.0f + 1e-5f);

  float gg1v[4], bo1v[4];
  float wx[4][3];
  #pragma unroll
  for (int nt = 0; nt < 4; ++nt) {
    int o = (nt >> 1) * 128 + 32 * w + (nt & 1) * 16 + l15;
    gg1v[nt] = g1[o] * inv; bo1v[nt] = b1[o];
    #pragma unroll
    for (int c = 0; c < 3; ++c) wx[nt][c] = W1g[o * 131 + c];
  }
  float gg2v[2], bo2v[2];
  #pragma unroll
  for (int nt = 0; nt < 2; ++nt) {
    int p = 32 * w + nt * 16 + l15;
    gg2v[nt] = g2[p] * inv; bo2v[nt] = b2[p];
  }
  const float g3c = g3[0] * inv, b3c = b3[0];
  const float xn0 = xyz[(size_t)bn*3+0], xn1 = xyz[(size_t)bn*3+1], xn2 = xyz[(size_t)bn*3+2];

  auto STAGE = [&](int sl) {
    const char* gp = (sl < 8 ? w1p + (size_t)sl * 8192
                             : w2p + (size_t)(sl - 8) * 8192) + t * 16;
    char* lp = lds + OFF_W + ((sl & 1) << 13) + (w << 10);
    gl_lds16(gp, lp);
    gl_lds16(gp + 4096, lp + 4096);
  };

  f32x4 acc1[4][4];
  f32x4 acc2[4][2] = {};

  // ---- prologue ----
  STAGE(0);
  if (t < 64) ((int*)(lds + OFF_IDX))[t] = (int)idxg[(size_t)bn * 64 + t];
  if (t < 64) ((unsigned*)(lds + OFF_QF))[t] =
      ((const unsigned*)(feat16 + (size_t)bn * C_))[t];
  if (t < 128) ((float*)(lds + OFF_W3))[t] = W3g[t];
  __syncthreads();

  const int* idxl = (const int*)(lds + OFF_IDX);

  // gather: h = (p16 - q16)^2 via packed f16 math, b128 LDS writes.
  // thread t -> sample s = t&63, slot g = t>>6 (32 channels).
  {
    int s = t & 63, g = t >> 6;
    int m = idxl[s];
    const f16* pb = feat16 + ((size_t)b * N_ + m) * C_ + g * 32;
    const f16* qb = (const f16*)(lds + OFF_QF) + g * 32;
    const unsigned sw = ((unsigned)((s >> 1) & 7)) << 4;
    const unsigned base = (unsigned)(g * 4096) ;
    #pragma unroll
    for (int qq = 0; qq < 4; ++qq) {
      f16x8 p = *(const f16x8*)(pb + qq * 8);
      f16x8 q = *(const f16x8*)(qb + qq * 8);
      f16x8 d = p - q;
      f16x8 hh = d * d;
      unsigned byte = base
        + ((((unsigned)(s * 64 + qq * 16)) ^ sw ^ ((unsigned)((g & 3) << 4))));
      *(f16x8*)(lds + OFF_H + byte) = hh;
    }
  }
  // gather xyz -> GX (relative coords; also feeds VALU z1 contribution)
  if (t < 192) {
    int s = t & 63, c = t >> 6;
    int m = idxl[s];
    float p = xyz[((size_t)b * N_ + m) * 3 + c];
    float xnc = (c == 0) ? xn0 : (c == 1 ? xn1 : xn2);
    ((float*)(lds + OFF_GX))[s * 3 + c] = p - xnc;
  }
  asm volatile("s_waitcnt vmcnt(0)" ::: "memory");
  __syncthreads();

  // ---- xyz-channel contribution: acc1 init on VALU (h_xyz = (p - 2*xn)^2) ----
  {
    const float* gx = (const float*)(lds + OFF_GX);
    #pragma unroll
    for (int mt = 0; mt < 4; ++mt)
      #pragma unroll
      for (int r = 0; r < 4; ++r) {
        int s = mt * 16 + lg * 4 + r;
        float d0 = gx[s * 3 + 0] - xn0;
        float d1 = gx[s * 3 + 1] - xn1;
        float d2 = gx[s * 3 + 2] - xn2;
        d0 *= d0; d1 *= d1; d2 *= d2;
        #pragma unroll
        for (int nt = 0; nt < 4; ++nt)
          acc1[mt][nt][r] = fmaf(wx[nt][0], d0, fmaf(wx[nt][1], d1, wx[nt][2] * d2));
      }
  }

  // ---- GEMM1: 8 phases (g 0..3 x oh 0..1) ----
  f16x8 af[4];
  #pragma unroll
  for (int p = 0; p < 8; ++p) {
    const int g = p >> 1, oh = p & 1;
    STAGE(p + 1);
    if (oh == 0) {
      const char* hb = lds + OFF_H + g * 4096;
      const unsigned gx4 = ((unsigned)(g & 3)) << 4;
      #pragma unroll
      for (int mt = 0; mt < 4; ++mt)
        af[mt] = *(const f16x8*)(hb + mt * 1024 + (labase ^ gx4));
    }
    const char* wb = lds + OFF_W + ((p & 1) << 13);
    f16x8 bf0 = *(const f16x8*)(wb + (32 * w) * 64 + labase);
    f16x8 bf1 = *(const f16x8*)(wb + (32 * w + 16) * 64 + labase);
    __builtin_amdgcn_s_setprio(1);
    #pragma unroll
    for (int mt = 0; mt < 4; ++mt) {
      acc1[mt][oh * 2 + 0] =
          __builtin_amdgcn_mfma_f32_16x16x32_f16(af[mt], bf0, acc1[mt][oh * 2 + 0], 0, 0, 0);
      acc1[mt][oh * 2 + 1] =
          __builtin_amdgcn_mfma_f32_16x16x32_f16(af[mt], bf1, acc1[mt][oh * 2 + 1], 0, 0, 0);
    }
    __builtin_amdgcn_s_setprio(0);
    asm volatile("s_waitcnt vmcnt(0)" ::: "memory");
    __syncthreads();
  }

  // ---- epilogue1: a1 (f16 singles) -> h region; wave w owns o-group w ----
  auto EPI1 = [&](int hf) {
    #pragma unroll
    for (int mt = 0; mt < 4; ++mt)
      #pragma unroll
      for (int nt2 = 0; nt2 < 2; ++nt2) {
        const int nt = hf * 2 + nt2;
        #pragma unroll
        for (int r = 0; r < 4; ++r) {
          int s = mt * 16 + lg * 4 + r;
          float a = fmaf(acc1[mt][nt][r], gg1v[nt], bo1v[nt]);
          a = a > 0.0f ? a : 0.0f;
          unsigned byte = (unsigned)(w * 4096)
            + (((unsigned)(s * 64 + nt2 * 32 + l15 * 2)) ^ ((unsigned)(((s >> 1) & 7) << 4))
               ^ ((unsigned)((w & 3) << 4)));
          *(f16*)(lds + OFF_H + byte) = (f16)a;
        }
      }
  };
  EPI1(0);
  __syncthreads();

  // ---- GEMM2: 8 phases, a1 half-split at ko==4 ----
  #pragma unroll
  for (int ko = 0; ko < 8; ++ko) {
    if (ko < 7) STAGE(9 + ko);
    const char* ab = lds + OFF_H + (ko & 3) * 4096;
    const unsigned gx4 = ((unsigned)(ko & 3)) << 4;
    f16x8 a2f[4];
    #pragma unroll
    for (int mt = 0; mt < 4; ++mt)
      a2f[mt] = *(const f16x8*)(ab + mt * 1024 + (labase ^ gx4));
    const char* wb = lds + OFF_W + ((ko & 1) << 13);
    f16x8 bf0 = *(const f16x8*)(wb + (32 * w) * 64 + labase);
    f16x8 bf1 = *(const f16x8*)(wb + (32 * w + 16) * 64 + labase);
    __builtin_amdgcn_s_setprio(1);
    #pragma unroll
    for (int mt = 0; mt < 4; ++mt) {
      acc2[mt][0] =
          __builtin_amdgcn_mfma_f32_16x16x32_f16(a2f[mt], bf0, acc2[mt][0], 0, 0, 0);
      acc2[mt][1] =
          __builtin_amdgcn_mfma_f32_16x16x32_f16(a2f[mt], bf1, acc2[mt][1], 0, 0, 0);
    }
    __builtin_amdgcn_s_setprio(0);
    asm volatile("s_waitcnt vmcnt(0)" ::: "memory");
    __syncthreads();
    if (ko == 3) {       // a1 half0 consumed -> write half1
      EPI1(1);
      __syncthreads();
    }
  }

  // ---- epilogue2: a2 = relu(bn2(z2)) f32, rows stride 528B (overlays H+W) ----
  #pragma unroll
  for (int mt = 0; mt < 4; ++mt)
    #pragma unroll
    for (int nt2 = 0; nt2 < 2; ++nt2) {
      int p2 = 32 * w + nt2 * 16 + l15;
      #pragma unroll
      for (int r = 0; r < 4; ++r) {
        int s = mt * 16 + lg * 4 + r;
        float a = fmaf(acc2[mt][nt2][r], gg2v[nt2], bo2v[nt2]);
        a = a > 0.0f ? a : 0.0f;
        *(float*)(lds + OFF_A2 + s * 528 + p2 * 4) = a;
      }
    }
  __syncthreads();

  // ---- GEMM3 + weighted mean ----
  {
    int s3 = t >> 2, q3 = t & 3;
    const float* a2row = (const float*)(lds + OFF_A2) + s3 * 132;
    const float* w3r = (const float*)(lds + OFF_W3);
    float z3 = 0.0f;
    #pragma unroll
    for (int i = 0; i < 8; ++i) {
      f32x4 av = *(const f32x4*)(a2row + q3 * 32 + i * 4);
      f32x4 wv = *(const f32x4*)(w3r + q3 * 32 + i * 4);
      z3 = fmaf(av[0], wv[0], z3); z3 = fmaf(av[1], wv[1], z3);
      z3 = fmaf(av[2], wv[2], z3); z3 = fmaf(av[3], wv[3], z3);
    }
    z3 += __shfl_xor(z3, 1);
    z3 += __shfl_xor(z3, 2);
    float wgt = fmaf(g3c, z3, b3c);
    wgt = wgt > 0.0f ? wgt : 0.0f;
    float v0 = 0.f, v1 = 0.f, v2 = 0.f, v3 = 0.f;
    if (q3 == 0) {
      const float* gx = (const float*)(lds + OFF_GX) + s3 * 3;
      v0 = gx[0] * wgt; v1 = gx[1] * wgt; v2 = gx[2] * wgt; v3 = wgt;
    }
    #pragma unroll
    for (int off = 4; off < 64; off <<= 1) {
      v0 += __shfl_xor(v0, off); v1 += __shfl_xor(v1, off);
      v2 += __shfl_xor(v2, off); v3 += __shfl_xor(v3, off);
    }
    if (lane == 0) {
      float* red = (float*)(lds + OFF_RED);
      red[w * 4 + 0] = v0; red[w * 4 + 1] = v1;
      red[w * 4 + 2] = v2; red[w * 4 + 3] = v3;
    }
    __syncthreads();
    if (t == 0) {
      const float* red = (const float*)(lds + OFF_RED);
      float n0 = red[0] + red[4] + red[8]  + red[12];
      float n1 = red[1] + red[5] + red[9]  + red[13];
      float n2 = red[2] + red[6] + red[10] + red[14];
      float dd = red[3] + red[7] + red[11] + red[15];
      out[(size_t)(b * 3 + 0) * N_ + n] = n0 / dd;
      out[(size_t)(b * 3 + 1) * N_ + n] = n1 / dd;
      out[(size_t)(b * 3 + 2) * N_ + n] = n2 / dd;
    }
  }
}

extern "C" void kernel_launch(void* const* d_in, const int* in_sizes, int n_in,
                              void* d_out, int out_size, void* d_ws, size_t ws_size,
                              hipStream_t stream) {
  (void)in_sizes; (void)n_in; (void)out_size; (void)ws_size;
  const float* xyz      = (const float*)d_in[0];
  const float* features = (const float*)d_in[1];
  const float* W1 = (const float*)d_in[2];
  const float* W2 = (const float*)d_in[3];
  const float* W3 = (const float*)d_in[4];
  const float* g1 = (const float*)d_in[5];
  const float* g2 = (const float*)d_in[6];
  const float* g3 = (const float*)d_in[7];
  const float* b1 = (const float*)d_in[8];
  const float* b2 = (const float*)d_in[9];
  const float* b3 = (const float*)d_in[10];
  float* out = (float*)d_out;

  char* ws = (char*)d_ws;
  f16* feat16         = (f16*)(ws + WS_FEAT16);
  unsigned short* idx = (unsigned short*)(ws + WS_IDX);
  char* W1p           = ws + WS_W1P;
  char* W2p           = ws + WS_W2P;

  prep_kernel<<<dim3((B_ * C_ * N_) / 256), dim3(256), 0, stream>>>(
      features, W1, W2, feat16, W1p, W2p);
  ballquery_kernel<<<dim3(B_ * N_ / 4), dim3(256), 0, stream>>>(xyz, idx);
  mlp_kernel<<<dim3(B_ * N_), dim3(256), 0, stream>>>(
      xyz, feat16, W1p, W2p, idx, W1, W3, g1, b1, g2, b2, g3, b3, out);
}

// Round 14
// 136.160 us; speedup vs baseline: 1.6825x; 1.0388x over previous
//
#include <hip/hip_runtime.h>
#include <math.h>

typedef _Float16 f16;
typedef _Float16 f16x8 __attribute__((ext_vector_type(8)));
typedef _Float16 f16x4 __attribute__((ext_vector_type(4)));
typedef float f32x4 __attribute__((ext_vector_type(4)));

#define B_  4
#define N_  2048
#define C_  128
#define NS_ 64

// ---- workspace layout (bytes) ----
#define WS_FEAT16 0u          // B*N*C f16 = 2097152
#define WS_IDX    2097152u    // B*N*NS u16 = 1048576
#define WS_W1X    3145728u    // [256 o][8 slots] = 8192
#define WS_W1P    3153920u    // 4 slices * 16384 = 65536
#define WS_W2P    3219456u    // 4 slices * 16384 = 65536

// ---- mlp LDS layout (bytes), total 53248 -> 3 blocks/CU ----
#define OFF_H   0             // h: 4 groups x 4096 = 16384 (a1 halves overlay)
#define OFF_HX  16384         // xyz half-group [64 s][32B] = 2048
#define OFF_W   18432         // weight dbuf 2 x 16384 (ends 51200)
#define OFF_A2  0             // 64*528 = 33792 f32 (overlays H/HX/W at the end)
#define OFF_GX  51200         // [64][3] f32 = 768
#define OFF_QF  51968         // [128] f16 = 256 (512 reserved)
#define OFF_IDX 52480         // 256 (RED overlays after gather)
#define OFF_RED 52480
#define OFF_W3  52736         // 512
#define LDS_TOTAL 53248

__device__ __forceinline__ void gl_lds16(const char* gp, char* lp) {
  __builtin_amdgcn_global_load_lds(
      (const __attribute__((address_space(1))) unsigned int*)gp,
      (__attribute__((address_space(3))) unsigned int*)lp, 16, 0, 0);
}

// pack two floats as adjacent f16 (RTN)
__device__ __forceinline__ unsigned pk2(float a, float b) {
  union { f16 h[2]; unsigned u; } cv;
  cv.h[0] = (f16)a; cv.h[1] = (f16)b;
  return cv.u;
}

// ---------------------------------------------------------------------------
// prep: feat (B,C,N) f32 -> feat16 (B,N,C) f16; W1 feature-cols -> 4 K-slices
// (32 ch) [256 o][16 pair-slots] swizzled 16KB; W1 xyz-cols -> [256 o][8
// slots] linear 8KB; W2 -> 4 K-slices (64 ch) [128 p][32 slots] swizzled
// 16KB. Weight images are exact LDS bytes for linear global_load_lds.
// ---------------------------------------------------------------------------
__global__ __launch_bounds__(256) void prep_kernel(
    const float* __restrict__ feat, const float* __restrict__ W1,
    const float* __restrict__ W2, f16* __restrict__ feat16,
    char* __restrict__ W1x, char* __restrict__ W1p, char* __restrict__ W2p)
{
  int i = blockIdx.x * 256 + threadIdx.x;
  {
    int n = i & (N_ - 1);
    int bc = i >> 11;
    int c = bc & (C_ - 1);
    int b = bc >> 7;
    feat16[(size_t)((b << 11) + n) * C_ + c] = (f16)feat[i];
  }
  if (i < 16384) {   // W1 feature: g slice, [o 0..255][j 0..15]; ch = 3+32g+2j
    int g = i >> 12, r = i & 4095, o = r >> 4, j = r & 15;
    const float* row = W1 + o * 131 + 3 + g * 32 + 2 * j;
    unsigned byte = ((unsigned)(o * 64 + j * 4)) ^ ((unsigned)(((o >> 1) & 7) << 4));
    *(unsigned*)(W1p + (size_t)g * 16384 + byte) = pk2(row[0], row[1]);
  }
  if (i < 16384) {   // W2: ko slice, [p 0..127][j 0..31]; o = 64ko+2j
    int ko = i >> 12, r = i & 4095, p = r >> 5, j = r & 31;
    int o = ko * 64 + 2 * j;
    unsigned byte = ((unsigned)(p * 128 + j * 4)) ^ ((unsigned)(((p >> 1) & 7) << 4));
    *(unsigned*)(W2p + (size_t)ko * 16384 + byte) = pk2(W2[p * 256 + o], W2[p * 256 + o + 1]);
  }
  if (i < 2048) {    // W1 xyz: [256 o][8 slots] linear
    int o = i >> 3, j = i & 7;
    unsigned v = 0;
    if (j == 0)      v = pk2(W1[o * 131 + 0], W1[o * 131 + 1]);
    else if (j == 1) v = pk2(W1[o * 131 + 2], 0.0f);
    *(unsigned*)(W1x + o * 32 + j * 4) = v;
  }
}

// ---------------------------------------------------------------------------
// ball query (fp64-exact membership), output u16
// ---------------------------------------------------------------------------
__global__ __launch_bounds__(256) void ballquery_kernel(
    const float* __restrict__ xyz, unsigned short* __restrict__ idxout)
{
  __shared__ float  xl[N_ * 3];
  __shared__ double sq[N_];
  __shared__ int    ibuf[4][NS_];

  const int b  = blockIdx.x >> 9;
  const int ng = blockIdx.x & 511;
  const int t  = threadIdx.x;
  const float* xb = xyz + (size_t)b * N_ * 3;

  for (int i = t; i < N_ * 3; i += 256) xl[i] = xb[i];
  __syncthreads();
  for (int i = t; i < N_; i += 256) {
    double x = (double)xl[3*i], y = (double)xl[3*i+1], z = (double)xl[3*i+2];
    sq[i] = x*x + y*y + z*z;
  }
  __syncthreads();

  const int wv = t >> 6, lane = t & 63;
  const int n = ng * 4 + wv;
  const double xn = (double)xl[3*n], yn = (double)xl[3*n+1], zn = (double)xl[3*n+2];
  const double sn = sq[n];

  int cnt = 0;
  for (int mb = 0; mb < N_; mb += 64) {
    int m = mb + lane;
    double dot = xn*(double)xl[3*m] + yn*(double)xl[3*m+1] + zn*(double)xl[3*m+2];
    double d2 = (sn + sq[m]) - 2.0 * dot;
    bool hit = d2 < 0.0625;
    unsigned long long mask = __ballot(hit);
    int pos = __popcll(mask & ((1ULL << lane) - 1ULL));
    int slot = cnt + pos;
    if (hit && slot < NS_) ibuf[wv][slot] = m;
    cnt += (int)__popcll(mask);
    if (cnt >= NS_) break;
  }
  asm volatile("s_waitcnt lgkmcnt(0)" ::: "memory");
  int total = cnt < NS_ ? cnt : NS_;
  int v = ibuf[wv][lane < total ? lane : 0];
  idxout[((size_t)b * N_ + n) * NS_ + lane] = (unsigned short)v;
}

// ---------------------------------------------------------------------------
// MLP: pure-f16 MFMA, 9 merged phases with counted-vmcnt dbuf pipeline
// (never drains mid-loop). Phase 0: xyz K=16 via mfma 16x16x16f16 (inits
// acc1, replaces 288-op VALU init). Phases 1-4: GEMM1 K=32 x all 256 o.
// Phases 5-8: GEMM2 K=64, a1 half-split. Per phase: STAGE(next->other buf);
// vmcnt(4); bar; W-frag reads; lgkm0; bar; a-frag reads; MFMA.
// 53248B LDS -> 3 blocks/CU; (256,3) bounds (no spill, R5/R11-proven).
// ---------------------------------------------------------------------------
__global__ __launch_bounds__(256, 3) void mlp_kernel(
    const float* __restrict__ xyz, const f16* __restrict__ feat16,
    const char* __restrict__ w1x, const char* __restrict__ w1p,
    const char* __restrict__ w2p,
    const unsigned short* __restrict__ idxg,
    const float* __restrict__ W3g,
    const float* __restrict__ g1, const float* __restrict__ b1,
    const float* __restrict__ g2, const float* __restrict__ b2,
    const float* __restrict__ g3, const float* __restrict__ b3,
    float* __restrict__ out)
{
  __shared__ __attribute__((aligned(128))) char lds[LDS_TOTAL];

  const int bidRaw = blockIdx.x;
  const int bn = ((bidRaw & 7) << 10) + (bidRaw >> 3);   // XCD swizzle (bijective)
  const int b = bn >> 11;
  const int n = bn & (N_ - 1);
  const int t = threadIdx.x;
  const int w = t >> 6, lane = t & 63;
  const int l15 = lane & 15, lg = lane >> 4;
  const unsigned swzl = (unsigned)(((l15 >> 1) & 7) << 4);
  const unsigned labase = ((unsigned)(l15 * 64 + lg * 16)) ^ swzl;
  const unsigned w2b0 = ((unsigned)(l15 * 128 + lg * 16)) ^ swzl;        // k 0..31
  const unsigned w2b1 = ((unsigned)(l15 * 128 + 64 + lg * 16)) ^ swzl;   // k 32..63
  const float inv = 1.0f / sqrtf(1.0f + 1e-5f);

  float gg1v[4], bo1v[4];
  #pragma unroll
  for (int nt = 0; nt < 4; ++nt) {
    int o = (nt >> 1) * 128 + 32 * w + (nt & 1) * 16 + l15;
    gg1v[nt] = g1[o] * inv; bo1v[nt] = b1[o];
  }
  float gg2v[2], bo2v[2];
  #pragma unroll
  for (int nt = 0; nt < 2; ++nt) {
    int p = 32 * w + nt * 16 + l15;
    gg2v[nt] = g2[p] * inv; bo2v[nt] = b2[p];
  }
  const float g3c = g3[0] * inv, b3c = b3[0];
  const float xn0 = xyz[(size_t)bn*3+0], xn1 = xyz[(size_t)bn*3+1], xn2 = xyz[(size_t)bn*3+2];

  // slices: 0 = W1x (8KB, 2 loads), 1..4 = W1 g (16KB, 4), 5..8 = W2 k (16KB, 4)
  auto STAGE = [&](int sl) {
    const char* gp; int nloads;
    if (sl == 0)      { gp = w1x;                          nloads = 2; }
    else if (sl <= 4) { gp = w1p + (size_t)(sl - 1) * 16384; nloads = 4; }
    else              { gp = w2p + (size_t)(sl - 5) * 16384; nloads = 4; }
    gp += t * 16;
    char* lp = lds + OFF_W + ((sl & 1) << 14) + (w << 10);
    for (int i = 0; i < nloads; ++i)
      gl_lds16(gp + i * 4096, lp + i * 4096);
  };

  f32x4 acc1[4][4];
  f32x4 acc2[4][2] = {};

  // ---- prologue ----
  STAGE(0);
  if (t < 64) ((int*)(lds + OFF_IDX))[t] = (int)idxg[(size_t)bn * 64 + t];
  if (t < 64) ((unsigned*)(lds + OFF_QF))[t] =
      ((const unsigned*)(feat16 + (size_t)bn * C_))[t];
  if (t < 128) ((float*)(lds + OFF_W3))[t] = W3g[t];
  __syncthreads();

  const int* idxl = (const int*)(lds + OFF_IDX);

  // feature gather: h = (p16 - q16)^2 packed f16; thread t -> (s = t&63, g = t>>6)
  {
    int s = t & 63, g = t >> 6;
    int m = idxl[s];
    const f16* pb = feat16 + ((size_t)b * N_ + m) * C_ + g * 32;
    const f16* qb = (const f16*)(lds + OFF_QF) + g * 32;
    const unsigned sw = ((unsigned)((s >> 1) & 7)) << 4;
    const unsigned base = (unsigned)(g * 4096);
    #pragma unroll
    for (int qq = 0; qq < 4; ++qq) {
      f16x8 p = *(const f16x8*)(pb + qq * 8);
      f16x8 q = *(const f16x8*)(qb + qq * 8);
      f16x8 d = p - q;
      f16x8 hh = d * d;
      unsigned byte = base
        + ((((unsigned)(s * 64 + qq * 16)) ^ sw ^ ((unsigned)((g & 3) << 4))));
      *(f16x8*)(lds + OFF_H + byte) = hh;
    }
  }
  // xyz gather: GX (f32 relative) + hx half-group (f16)
  if (t < 64) {
    int s = t;
    int m = idxl[s];
    const float* pm = xyz + ((size_t)b * N_ + m) * 3;
    float p0 = pm[0], p1 = pm[1], p2c = pm[2];
    float* gxp = (float*)(lds + OFF_GX) + s * 3;
    gxp[0] = p0 - xn0; gxp[1] = p1 - xn1; gxp[2] = p2c - xn2;
    float h0 = p0 - 2.0f * xn0; h0 *= h0;
    float h1 = p1 - 2.0f * xn1; h1 *= h1;
    float h2 = p2c - 2.0f * xn2; h2 *= h2;
    char* hx = lds + OFF_HX + s * 32;
    *(unsigned*)(hx + 0)  = pk2(h0, h1);
    *(unsigned*)(hx + 4)  = pk2(h2, 0.0f);
    *(unsigned*)(hx + 8)  = 0u;
    *(unsigned*)(hx + 12) = 0u;
    f32x4 z4 = {0.0f, 0.0f, 0.0f, 0.0f};
    *(f32x4*)(hx + 16) = z4;
  }

  // ---- phase 0: xyz K=16 (reads hx + W1x in buf0), inits acc1 ----
  STAGE(1);
  asm volatile("s_waitcnt vmcnt(4) lgkmcnt(0)" ::: "memory");
  __builtin_amdgcn_s_barrier();
  {
    const char* wbx = lds + OFF_W;   // buf0, first 8KB
    f16x4 bf4[4];
    #pragma unroll
    for (int nt = 0; nt < 4; ++nt) {
      int orow = (nt >> 1) * 128 + 32 * w + (nt & 1) * 16 + l15;
      bf4[nt] = *(const f16x4*)(wbx + orow * 32 + lg * 8);
    }
    asm volatile("s_waitcnt lgkmcnt(0)" ::: "memory");
    __builtin_amdgcn_s_barrier();
    f16x4 af4[4];
    #pragma unroll
    for (int mt = 0; mt < 4; ++mt)
      af4[mt] = *(const f16x4*)(lds + OFF_HX + (16 * mt + l15) * 32 + lg * 8);
    const f32x4 z4 = {0.0f, 0.0f, 0.0f, 0.0f};
    #pragma unroll
    for (int mt = 0; mt < 4; ++mt)
      #pragma unroll
      for (int nt = 0; nt < 4; ++nt)
        acc1[mt][nt] = __builtin_amdgcn_mfma_f32_16x16x16f16(af4[mt], bf4[nt], z4, 0, 0, 0);
  }

  // ---- phases 1..4: GEMM1 K=32 each, all 256 o ----
  #pragma unroll
  for (int g = 0; g < 4; ++g) {
    const int sl = 1 + g;
    STAGE(sl + 1);
    asm volatile("s_waitcnt vmcnt(4) lgkmcnt(0)" ::: "memory");
    __builtin_amdgcn_s_barrier();
    const char* wb = lds + OFF_W + ((sl & 1) << 14);
    f16x8 bf[4];
    #pragma unroll
    for (int nt = 0; nt < 4; ++nt) {
      int ob = (nt >> 1) * 128 + 32 * w + (nt & 1) * 16;
      bf[nt] = *(const f16x8*)(wb + ob * 64 + labase);
    }
    asm volatile("s_waitcnt lgkmcnt(0)" ::: "memory");
    __builtin_amdgcn_s_barrier();
    const char* hb = lds + OFF_H + g * 4096;
    const unsigned gx4 = ((unsigned)g) << 4;
    f16x8 af[4];
    #pragma unroll
    for (int mt = 0; mt < 4; ++mt)
      af[mt] = *(const f16x8*)(hb + mt * 1024 + (labase ^ gx4));
    __builtin_amdgcn_s_setprio(1);
    #pragma unroll
    for (int mt = 0; mt < 4; ++mt)
      #pragma unroll
      for (int nt = 0; nt < 4; ++nt)
        acc1[mt][nt] = __builtin_amdgcn_mfma_f32_16x16x32_f16(af[mt], bf[nt], acc1[mt][nt], 0, 0, 0);
    __builtin_amdgcn_s_setprio(0);
  }

  // ---- epilogue1 half0 (a1 o<128 -> h slots; wave w -> slot w) ----
  auto EPI1 = [&](int hf) {
    #pragma unroll
    for (int mt = 0; mt < 4; ++mt)
      #pragma unroll
      for (int nt2 = 0; nt2 < 2; ++nt2) {
        const int nt = hf * 2 + nt2;
        #pragma unroll
        for (int r = 0; r < 4; ++r) {
          int s = mt * 16 + lg * 4 + r;
          float a = fmaf(acc1[mt][nt][r], gg1v[nt], bo1v[nt]);
          a = a > 0.0f ? a : 0.0f;
          unsigned byte = (unsigned)(w * 4096)
            + (((unsigned)(s * 64 + nt2 * 32 + l15 * 2)) ^ ((unsigned)(((s >> 1) & 7) << 4))
               ^ ((unsigned)((w & 3) << 4)));
          *(f16*)(lds + OFF_H + byte) = (f16)a;
        }
      }
  };
  asm volatile("s_waitcnt lgkmcnt(0)" ::: "memory");   // all af reads done
  __builtin_amdgcn_s_barrier();
  EPI1(0);
  asm volatile("s_waitcnt lgkmcnt(0)" ::: "memory");
  __builtin_amdgcn_s_barrier();

  // ---- phases 5..8: GEMM2 K=64 each, a1 half-split after phase 6 ----
  #pragma unroll
  for (int k = 0; k < 4; ++k) {
    const int sl = 5 + k;
    if (sl < 8) {
      STAGE(sl + 1);
      asm volatile("s_waitcnt vmcnt(4) lgkmcnt(0)" ::: "memory");
    } else {
      asm volatile("s_waitcnt vmcnt(0) lgkmcnt(0)" ::: "memory");
    }
    __builtin_amdgcn_s_barrier();
    const char* wb = lds + OFF_W + ((sl & 1) << 14);
    f16x8 bq0[2], bq1[2];
    #pragma unroll
    for (int nt2 = 0; nt2 < 2; ++nt2) {
      int pb = (32 * w + nt2 * 16) * 128;
      bq0[nt2] = *(const f16x8*)(wb + pb + w2b0);
      bq1[nt2] = *(const f16x8*)(wb + pb + w2b1);
    }
    asm volatile("s_waitcnt lgkmcnt(0)" ::: "memory");
    __builtin_amdgcn_s_barrier();
    const int sl0 = (2 * k) & 3, sl1 = (2 * k + 1) & 3;
    f16x8 a0f[4], a1f[4];
    #pragma unroll
    for (int mt = 0; mt < 4; ++mt) {
      a0f[mt] = *(const f16x8*)(lds + OFF_H + sl0 * 4096 + mt * 1024 + (labase ^ (unsigned)(sl0 << 4)));
      a1f[mt] = *(const f16x8*)(lds + OFF_H + sl1 * 4096 + mt * 1024 + (labase ^ (unsigned)(sl1 << 4)));
    }
    __builtin_amdgcn_s_setprio(1);
    #pragma unroll
    for (int mt = 0; mt < 4; ++mt)
      #pragma unroll
      for (int nt2 = 0; nt2 < 2; ++nt2) {
        f32x4 c = acc2[mt][nt2];
        c = __builtin_amdgcn_mfma_f32_16x16x32_f16(a0f[mt], bq0[nt2], c, 0, 0, 0);
        c = __builtin_amdgcn_mfma_f32_16x16x32_f16(a1f[mt], bq1[nt2], c, 0, 0, 0);
        acc2[mt][nt2] = c;
      }
    __builtin_amdgcn_s_setprio(0);
    if (k == 1) {   // slots 0..3 consumed -> write a1 half1 (o 128..255)
      asm volatile("s_waitcnt lgkmcnt(0)" ::: "memory");
      __builtin_amdgcn_s_barrier();
      EPI1(1);
      asm volatile("s_waitcnt lgkmcnt(0)" ::: "memory");
      __builtin_amdgcn_s_barrier();
    }
  }
  asm volatile("s_waitcnt lgkmcnt(0)" ::: "memory");   // phase8 a-reads done
  __builtin_amdgcn_s_barrier();

  // ---- epilogue2: a2 = relu(bn2(z2)) f32, rows stride 528B (overlays H/W) ----
  #pragma unroll
  for (int mt = 0; mt < 4; ++mt)
    #pragma unroll
    for (int nt2 = 0; nt2 < 2; ++nt2) {
      int p2 = 32 * w + nt2 * 16 + l15;
      #pragma unroll
      for (int r = 0; r < 4; ++r) {
        int s = mt * 16 + lg * 4 + r;
        float a = fmaf(acc2[mt][nt2][r], gg2v[nt2], bo2v[nt2]);
        a = a > 0.0f ? a : 0.0f;
        *(float*)(lds + OFF_A2 + s * 528 + p2 * 4) = a;
      }
    }
  asm volatile("s_waitcnt lgkmcnt(0)" ::: "memory");
  __builtin_amdgcn_s_barrier();

  // ---- GEMM3 + weighted mean ----
  {
    int s3 = t >> 2, q3 = t & 3;
    const float* a2row = (const float*)(lds + OFF_A2) + s3 * 132;
    const float* w3r = (const float*)(lds + OFF_W3);
    float z3 = 0.0f;
    #pragma unroll
    for (int i = 0; i < 8; ++i) {
      f32x4 av = *(const f32x4*)(a2row + q3 * 32 + i * 4);
      f32x4 wv = *(const f32x4*)(w3r + q3 * 32 + i * 4);
      z3 = fmaf(av[0], wv[0], z3); z3 = fmaf(av[1], wv[1], z3);
      z3 = fmaf(av[2], wv[2], z3); z3 = fmaf(av[3], wv[3], z3);
    }
    z3 += __shfl_xor(z3, 1);
    z3 += __shfl_xor(z3, 2);
    float wgt = fmaf(g3c, z3, b3c);
    wgt = wgt > 0.0f ? wgt : 0.0f;
    float v0 = 0.f, v1 = 0.f, v2 = 0.f, v3 = 0.f;
    if (q3 == 0) {
      const float* gx = (const float*)(lds + OFF_GX) + s3 * 3;
      v0 = gx[0] * wgt; v1 = gx[1] * wgt; v2 = gx[2] * wgt; v3 = wgt;
    }
    #pragma unroll
    for (int off = 4; off < 64; off <<= 1) {
      v0 += __shfl_xor(v0, off); v1 += __shfl_xor(v1, off);
      v2 += __shfl_xor(v2, off); v3 += __shfl_xor(v3, off);
    }
    if (lane == 0) {
      float* red = (float*)(lds + OFF_RED);
      red[w * 4 + 0] = v0; red[w * 4 + 1] = v1;
      red[w * 4 + 2] = v2; red[w * 4 + 3] = v3;
    }
    __syncthreads();
    if (t == 0) {
      const float* red = (const float*)(lds + OFF_RED);
      float n0 = red[0] + red[4] + red[8]  + red[12];
      float n1 = red[1] + red[5] + red[9]  + red[13];
      float n2 = red[2] + red[6] + red[10] + red[14];
      float dd = red[3] + red[7] + red[11] + red[15];
      out[(size_t)(b * 3 + 0) * N_ + n] = n0 / dd;
      out[(size_t)(b * 3 + 1) * N_ + n] = n1 / dd;
      out[(size_t)(b * 3 + 2) * N_ + n] = n2 / dd;
    }
  }
}

extern "C" void kernel_launch(void* const* d_in, const int* in_sizes, int n_in,
                              void* d_out, int out_size, void* d_ws, size_t ws_size,
                              hipStream_t stream) {
  (void)in_sizes; (void)n_in; (void)out_size; (void)ws_size;
  const float* xyz      = (const float*)d_in[0];
  const float* features = (const float*)d_in[1];
  const float* W1 = (const float*)d_in[2];
  const float* W2 = (const float*)d_in[3];
  const float* W3 = (const float*)d_in[4];
  const float* g1 = (const float*)d_in[5];
  const float* g2 = (const float*)d_in[6];
  const float* g3 = (const float*)d_in[7];
  const float* b1 = (const float*)d_in[8];
  const float* b2 = (const float*)d_in[9];
  const float* b3 = (const float*)d_in[10];
  float* out = (float*)d_out;

  char* ws = (char*)d_ws;
  f16* feat16         = (f16*)(ws + WS_FEAT16);
  unsigned short* idx = (unsigned short*)(ws + WS_IDX);
  char* W1x           = ws + WS_W1X;
  char* W1p           = ws + WS_W1P;
  char* W2p           = ws + WS_W2P;

  prep_kernel<<<dim3((B_ * C_ * N_) / 256), dim3(256), 0, stream>>>(
      features, W1, W2, feat16, W1x, W1p, W2p);
  ballquery_kernel<<<dim3(B_ * N_ / 4), dim3(256), 0, stream>>>(xyz, idx);
  mlp_kernel<<<dim3(B_ * N_), dim3(256), 0, stream>>>(
      xyz, feat16, W1x, W1p, W2p, idx, W3, g1, b1, g2, b2, g3, b3, out);
}